// Round 9
// baseline (188.860 us; speedup 1.0000x reference)
//
#include <hip/hip_runtime.h>

#define CT 256
#define KDIM 2304
#define COLP 296         // padded col row stride in shorts

typedef unsigned short u16;
typedef __attribute__((ext_vector_type(8))) short bf16x8;
typedef __attribute__((ext_vector_type(4))) float f32x4;
typedef __fp16 fp16x2 __attribute__((ext_vector_type(2)));

__device__ __forceinline__ unsigned f2b(float f) {       // f32 -> bf16 bits, RTE
    unsigned u = __float_as_uint(f);
    u += 0x7fffu + ((u >> 16) & 1u);
    return u >> 16;
}
__device__ __forceinline__ float lo_bf(unsigned u) { return __uint_as_float(u << 16); }
__device__ __forceinline__ float hi_bf(unsigned u) { return __uint_as_float(u & 0xffff0000u); }

// Fused prep: blocks [0,2048) = x -> xi (bf16 interleaved-8); [2048,2336) = W -> pw.
__global__ __launch_bounds__(256) void k_prep(const float* __restrict__ x, uint4* __restrict__ xi,
                                              const float* __restrict__ wgt, uint4* __restrict__ pw)
{
    if (blockIdx.x < 2048) {
        int u = blockIdx.x * 256 + threadIdx.x;        // [0, 524288)
        int bcg = u >> 12, p = u & 4095;
        const float* xp = x + (((size_t)bcg) << 15) + p;
        unsigned r[4];
#pragma unroll
        for (int i = 0; i < 4; ++i) {
            float a = xp[(size_t)(2 * i) << 12];
            float c = xp[(size_t)(2 * i + 1) << 12];
            r[i] = f2b(a) | (f2b(c) << 16);
        }
        uint4 o; o.x = r[0]; o.y = r[1]; o.z = r[2]; o.w = r[3];
        xi[u] = o;
    } else {
        int u = (blockIdx.x - 2048) * 256 + threadIdx.x;   // [0, 73728)
        int kc = u >> 10, rm = u & 1023;
        int m = rm >> 2, j = rm & 3;
        int round = kc / 9, tap = kc - round * 9;
        const float* src = wgt + (size_t)m * KDIM + tap;
        int c0 = round * 32 + j * 8;
        unsigned q[4];
#pragma unroll
        for (int i = 0; i < 4; ++i) {
            float a = src[(size_t)(c0 + 2 * i) * 9];
            float c = src[(size_t)(c0 + 2 * i + 1) * 9];
            q[i] = f2b(a) | (f2b(c) << 16);
        }
        uint4 o; o.x = q[0]; o.y = q[1]; o.z = q[2]; o.w = q[3];
        pw[u] = o;
    }
}

// Fused unfold + partial attention + partial MFMA GEMM. Split-K.
// Grid 1024: bx = rowblk*4 + half*2 + khalf. Block = 32 n x 256 m x 1152 k (4 rounds).
__global__ __launch_bounds__(512, 8) void k_main(const uint4* __restrict__ xi, const float* __restrict__ off,
                                                 const uint4* __restrict__ pw, const float* __restrict__ att_w,
                                                 float* __restrict__ pout0, float* __restrict__ pout1,
                                                 float* __restrict__ ap0, float* __restrict__ ap1)
{
    __shared__ uint2 s_wt[288];        // bilinear corner weights as 4 x f16
    __shared__ int2 s_off[288];        // packed corner positions
    __shared__ u16 Xs[7680];           // superplane window: <=15 rows x 64 pos x 8 ch
    __shared__ u16 col[32 * COLP];     // 32 n x 288 k (padded)

    int bx = blockIdx.x;
    int rowblk = bx >> 2, half = (bx >> 1) & 1, khalf = bx & 1;
    int b = rowblk >> 6, h = rowblk & 63, n0 = half * 32;
    float* pout = khalf ? pout1 : pout0;
    float* ap = khalf ? ap1 : ap0;
    int tid = threadIdx.x;
    int lane = tid & 63, w = tid >> 6;
    int l15 = lane & 15, kb = lane >> 4;
    int wm = w * 32;

    // bilinear coords for this block's 32 positions
    for (int e = tid; e < 288; e += 512) {
        int kk = e >> 5, wl = e & 31;
        int ww_ = n0 + wl;
        int ky = kk / 3, kx = kk - ky * 3;
        float dy = off[((size_t)(b * 18 + 2 * kk) * 64 + h) * 64 + ww_];
        float dx = off[((size_t)(b * 18 + 2 * kk + 1) * 64 + h) * 64 + ww_];
        float py = (float)(h + ky - 1) + dy;
        float px = (float)(ww_ + kx - 1) + dx;
        float y0f = floorf(py), x0f = floorf(px);
        int y0 = (int)y0f, x0 = (int)x0f;
        float fy = py - y0f, fx = px - x0f;
        float vy0 = (y0 >= 0 && y0 < 64) ? 1.f : 0.f;
        float vy1 = (y0 >= -1 && y0 < 63) ? 1.f : 0.f;
        float vx0 = (x0 >= 0 && x0 < 64) ? 1.f : 0.f;
        float vx1 = (x0 >= -1 && x0 < 63) ? 1.f : 0.f;
        float w0 = (1.f - fy) * (1.f - fx) * vy0 * vx0;
        float w1 = (1.f - fy) * fx * vy0 * vx1;
        float w2 = fy * (1.f - fx) * vy1 * vx0;
        float w3 = fy * fx * vy1 * vx1;
        fp16x2 pA = __builtin_amdgcn_cvt_pkrtz(w0, w1);
        fp16x2 pB = __builtin_amdgcn_cvt_pkrtz(w2, w3);
        uint2 wp;
        wp.x = __builtin_bit_cast(unsigned, pA);
        wp.y = __builtin_bit_cast(unsigned, pB);
        int yc0 = min(max(y0, 0), 63), yc1 = min(max(y0 + 1, 0), 63);
        int xc0 = min(max(x0, 0), 63), xc1 = min(max(x0 + 1, 0), 63);
        s_wt[e] = wp;
        s_off[e] = make_int2((yc0 * 64 + xc0) | ((yc0 * 64 + xc1) << 16),
                             (yc1 * 64 + xc0) | ((yc1 * 64 + xc1) << 16));
    }

    int r0 = max(0, h - 7), r1 = min(63, h + 7);
    int nrows = r1 - r0 + 1, nw = nrows * 64, rbase = r0 * 64;

    float att_acc = 0.f;
    f32x4 acc[2][2];
#pragma unroll
    for (int mt = 0; mt < 2; ++mt)
#pragma unroll
        for (int nt = 0; nt < 2; ++nt) acc[mt][nt] = (f32x4){0.f, 0.f, 0.f, 0.f};

    for (int rr = 0; rr < 4; ++rr) {
        int round = khalf * 4 + rr;
        for (int sp = 0; sp < 4; ++sp) {
            int cg = round * 4 + sp;
            size_t xibase = (size_t)(b * 32 + cg) << 12;
            __syncthreads();           // Xs free / col slice free
            for (int u2 = tid; u2 < nrows * 64; u2 += 512)
                ((uint4*)Xs)[u2] = xi[xibase + rbase + u2];
            __syncthreads();           // Xs ready
            for (int it = tid; it < 288; it += 512) {
                int tap = it >> 5, nn = it & 31;
                uint2 wp = s_wt[it];
                fp16x2 wA = __builtin_bit_cast(fp16x2, wp.x);
                fp16x2 wB = __builtin_bit_cast(fp16x2, wp.y);
                float wx = (float)wA[0], wy = (float)wA[1];
                float wz = (float)wB[0], ww2 = (float)wB[1];
                int2 of = s_off[it];
                int P00 = of.x & 0xffff, P01 = (of.x >> 16) & 0xffff;
                int P10 = of.y & 0xffff, P11 = (of.y >> 16) & 0xffff;
                uint4 c00, c01, c10, c11;
                int Q;
                Q = P00 - rbase;
                if ((unsigned)Q < (unsigned)nw) c00 = *(const uint4*)&Xs[Q * 8]; else c00 = xi[xibase + P00];
                Q = P01 - rbase;
                if ((unsigned)Q < (unsigned)nw) c01 = *(const uint4*)&Xs[Q * 8]; else c01 = xi[xibase + P01];
                Q = P10 - rbase;
                if ((unsigned)Q < (unsigned)nw) c10 = *(const uint4*)&Xs[Q * 8]; else c10 = xi[xibase + P10];
                Q = P11 - rbase;
                if ((unsigned)Q < (unsigned)nw) c11 = *(const uint4*)&Xs[Q * 8]; else c11 = xi[xibase + P11];
                const unsigned* a00 = (const unsigned*)&c00;
                const unsigned* a01 = (const unsigned*)&c01;
                const unsigned* a10 = (const unsigned*)&c10;
                const unsigned* a11 = (const unsigned*)&c11;
                unsigned o[4];
#pragma unroll
                for (int q = 0; q < 4; ++q) {
                    float v0 = wx * lo_bf(a00[q]) + wy * lo_bf(a01[q]) + wz * lo_bf(a10[q]) + ww2 * lo_bf(a11[q]);
                    float v1 = wx * hi_bf(a00[q]) + wy * hi_bf(a01[q]) + wz * hi_bf(a10[q]) + ww2 * hi_bf(a11[q]);
                    o[q] = f2b(v0) | (f2b(v1) << 16);
                }
                uint4 ov; ov.x = o[0]; ov.y = o[1]; ov.z = o[2]; ov.w = o[3];
                *(uint4*)&col[nn * COLP + tap * 32 + sp * 8] = ov;
            }
        }
        __syncthreads();               // full 288-k col slice ready

        // attention tap-max + dot: wave 0 only; lane = nn*2 + h2 (4 channels/lane, b64 reads)
        if (tid < 64) {
            int nn = tid >> 1, h2 = tid & 1;
#pragma unroll
            for (int sp = 0; sp < 4; ++sp) {
                const u16* base = &col[nn * COLP + sp * 8 + h2 * 4];
                float m0 = -1e30f, m1 = -1e30f, m2 = -1e30f, m3 = -1e30f;
#pragma unroll
                for (int t = 0; t < 9; ++t) {
                    uint2 v = *(const uint2*)(base + t * 32);
                    m0 = fmaxf(m0, lo_bf(v.x)); m1 = fmaxf(m1, hi_bf(v.x));
                    m2 = fmaxf(m2, lo_bf(v.y)); m3 = fmaxf(m3, hi_bf(v.y));
                }
                int cb = round * 32 + sp * 8 + h2 * 4;
                att_acc += att_w[cb] * m0 + att_w[cb + 1] * m1 + att_w[cb + 2] * m2 + att_w[cb + 3] * m3;
            }
        }

        // MFMA phase: no internal barriers (col stable; A streamed from L2)
#pragma unroll
        for (int ts = 0; ts < 9; ++ts) {
            int kc = round * 9 + ts;
            bf16x8 bf[2];
#pragma unroll
            for (int nt = 0; nt < 2; ++nt)
                bf[nt] = *(const bf16x8*)&col[(nt * 16 + l15) * COLP + ts * 32 + kb * 8];
#pragma unroll
            for (int mt = 0; mt < 2; ++mt) {
                uint4 a = pw[(size_t)kc * 1024 + (wm + mt * 16 + l15) * 4 + kb];
                bf16x8 af = __builtin_bit_cast(bf16x8, a);
#pragma unroll
                for (int nt = 0; nt < 2; ++nt)
                    acc[mt][nt] = __builtin_amdgcn_mfma_f32_16x16x32_bf16(af, bf[nt], acc[mt][nt], 0, 0, 0);
            }
        }
    }

    // store raw attention-logit partials (this K-half's 128 channels)
    if (tid < 64) {
        float v = att_acc + __shfl_xor(att_acc, 1);
        if ((tid & 1) == 0) ap[rowblk * 64 + n0 + (tid >> 1)] = v;
    }

    // store partial GEMM (un-gated)
#pragma unroll
    for (int mt = 0; mt < 2; ++mt)
#pragma unroll
        for (int nt = 0; nt < 2; ++nt)
#pragma unroll
            for (int r = 0; r < 4; ++r) {
                int m = wm + mt * 16 + kb * 4 + r;
                pout[(((size_t)(b * CT + m)) << 12) + h * 64 + n0 + nt * 16 + l15] = acc[mt][nt][r];
            }
}

// Fused combine + attention gate + GroupNorm + ReLU. One block per (b,g).
__global__ __launch_bounds__(256) void k_gn(const float* __restrict__ p0, const float* __restrict__ p1,
                                            const float* __restrict__ ap0, const float* __restrict__ ap1,
                                            const float* __restrict__ att_b, const float* __restrict__ gamma,
                                            const float* __restrict__ beta, float* __restrict__ outp)
{
    __shared__ float s_att[4096];
    __shared__ float rs1[4], rs2[4], s_stat[2];
    int bg = blockIdx.x, b = bg >> 5, g = bg & 31;
    int tid = threadIdx.x;
    float ab = att_b[0];
    for (int i = tid; i < 4096; i += 256) {
        float s = ab + ap0[b * 4096 + i] + ap1[b * 4096 + i];
        s_att[i] = 1.f / (1.f + expf(-s));
    }
    __syncthreads();

    size_t base4 = ((size_t)(b * CT + g * 8) << 12) >> 2;
    const float4* q0 = (const float4*)p0;
    const float4* q1 = (const float4*)p1;
    float4* o4 = (float4*)outp;
    float s1 = 0.f, s2 = 0.f;
    for (int i = tid; i < 8192; i += 256) {
        int pos4 = i & 1023;
        float4 a = q0[base4 + i], c = q1[base4 + i];
        float4 t = *(const float4*)&s_att[pos4 * 4];
        float4 v;
        v.x = (a.x + c.x) * t.x;
        v.y = (a.y + c.y) * t.y;
        v.z = (a.z + c.z) * t.z;
        v.w = (a.w + c.w) * t.w;
        o4[base4 + i] = v;
        s1 += (v.x + v.y) + (v.z + v.w);
        s2 += v.x * v.x + v.y * v.y + v.z * v.z + v.w * v.w;
    }
#pragma unroll
    for (int d = 1; d <= 32; d <<= 1) {
        s1 += __shfl_xor(s1, d);
        s2 += __shfl_xor(s2, d);
    }
    if ((tid & 63) == 0) { rs1[tid >> 6] = s1; rs2[tid >> 6] = s2; }
    __syncthreads();
    if (tid == 0) {
        float S1 = rs1[0] + rs1[1] + rs1[2] + rs1[3];
        float S2 = rs2[0] + rs2[1] + rs2[2] + rs2[3];
        float mean = S1 * (1.f / 32768.f);
        float var = S2 * (1.f / 32768.f) - mean * mean;
        s_stat[0] = mean;
        s_stat[1] = rsqrtf(var + 1e-5f);
    }
    __syncthreads();
    float mean = s_stat[0], rstd = s_stat[1];
    for (int i = tid; i < 8192; i += 256) {
        int c = g * 8 + (i >> 10);
        float ga = gamma[c], be = beta[c];
        float4 v = o4[base4 + i];
        float4 r;
        r.x = fmaxf((v.x - mean) * rstd * ga + be, 0.f);
        r.y = fmaxf((v.y - mean) * rstd * ga + be, 0.f);
        r.z = fmaxf((v.z - mean) * rstd * ga + be, 0.f);
        r.w = fmaxf((v.w - mean) * rstd * ga + be, 0.f);
        o4[base4 + i] = r;
    }
}

extern "C" void kernel_launch(void* const* d_in, const int* in_sizes, int n_in,
                              void* d_out, int out_size, void* d_ws, size_t ws_size,
                              hipStream_t stream)
{
    const float* x = (const float*)d_in[0];
    const float* off = (const float*)d_in[1];
    const float* wgt = (const float*)d_in[2];
    const float* attw = (const float*)d_in[3];
    const float* attb = (const float*)d_in[4];
    const float* gamma = (const float*)d_in[5];
    const float* beta = (const float*)d_in[6];
    float* outp = (float*)d_out;

    char* ws = (char*)d_ws;
    uint4* xi = (uint4*)ws;                          // 8.39 MB
    uint4* pw = (uint4*)(ws + 8388608);              // 1.18 MB
    float* pout0 = (float*)(ws + 9568256);           // 16.78 MB
    float* pout1 = (float*)(ws + 26345472);          // 16.78 MB
    float* ap0 = (float*)(ws + 43122688);            // 64 KB
    float* ap1 = (float*)(ws + 43188224);            // 64 KB

    k_prep<<<dim3(2336), dim3(256), 0, stream>>>(x, xi, wgt, pw);
    k_main<<<dim3(1024), dim3(512), 0, stream>>>(xi, off, pw, attw, pout0, pout1, ap0, ap1);
    k_gn<<<dim3(128), dim3(256), 0, stream>>>(pout0, pout1, ap0, ap1, attb, gamma, beta, outp);
}